// Round 9
// baseline (9443.610 us; speedup 1.0000x reference)
//
#include <hip/hip_runtime.h>
#include <hip/hip_bf16.h>

#define T_STEPS 800
#define BATCH   32
#define FEAT    161
#define UNITS   1024
#define CLIPV   20.0f

typedef __attribute__((ext_vector_type(8))) short short8;
typedef __attribute__((ext_vector_type(4))) float f32x4;
typedef unsigned short u16;
typedef unsigned int   u32;
typedef unsigned long long u64;

__device__ __forceinline__ float bf16_f(u16 u) {
    return __uint_as_float(((u32)u) << 16);
}
__device__ __forceinline__ u16 bf16_rn(float x) {
    __hip_bfloat16 b = __float2bfloat16(x);
    return *(u16*)&b;
}
__device__ __forceinline__ u64 ld_agent_u64(const u64* p) {
    return __hip_atomic_load(p, __ATOMIC_RELAXED, __HIP_MEMORY_SCOPE_AGENT);
}
__device__ __forceinline__ void st_agent_u64(u64* p, u64 v) {
    __hip_atomic_store(p, v, __ATOMIC_RELAXED, __HIP_MEMORY_SCOPE_AGENT);
}
__device__ __forceinline__ void st_agent_u32(u32* p, u32 v) {
    __hip_atomic_store(p, v, __ATOMIC_RELAXED, __HIP_MEMORY_SCOPE_AGENT);
}
__device__ __forceinline__ short8 ld_agent_b16x8(const u16* p) {
    union { u64 q[2]; short8 v; } u;
    u.q[0] = ld_agent_u64((const u64*)p);
    u.q[1] = ld_agent_u64((const u64*)p + 1);
    return u.v;
}
__device__ __forceinline__ float selv(f32x4 v, int r) {
    float s = v.x;
    s = (r == 1) ? v.y : s;
    s = (r == 2) ? v.z : s;
    s = (r == 3) ? v.w : s;
    return s;
}

// ---------------------------------------------------------------------------
// zero tagged h double-buffer (2 x 64 x 1024 u64; tag0|0.0f == 0) + flags
__global__ __launch_bounds__(256) void init_ws(u64* htag, u32* flags) {
    int gid = blockIdx.x * 256 + threadIdx.x;          // 16384 threads
    for (int i = gid; i < 2 * 64 * UNITS; i += 64 * 256) htag[i] = 0ull;
    if (gid < 128) flags[gid] = 0u;
}

// ---------------------------------------------------------------------------
// Ut splits: U[k][u] fp32 -> Ut1/2/3[u][k] bf16 (hi/mid/lo, 24-bit total)
__global__ __launch_bounds__(256) void u_split_t(const float* __restrict__ U,
                                                 u16* __restrict__ Ut1,
                                                 u16* __restrict__ Ut2,
                                                 u16* __restrict__ Ut3) {
    __shared__ float tile[32][33];
    int bx = blockIdx.x, by = blockIdx.y;
    int lx = threadIdx.x & 31;
    int ly4 = (threadIdx.x >> 5) * 4;
    #pragma unroll
    for (int j = 0; j < 4; ++j)
        tile[ly4 + j][lx] = U[(size_t)(by * 32 + ly4 + j) * UNITS + bx * 32 + lx];
    __syncthreads();
    #pragma unroll
    for (int j = 0; j < 4; ++j) {
        float x = tile[lx][ly4 + j];
        size_t o = (size_t)(bx * 32 + ly4 + j) * UNITS + by * 32 + lx;
        u16 s1 = bf16_rn(x);  float r1 = x - bf16_f(s1);
        u16 s2 = bf16_rn(r1); float r2 = r1 - bf16_f(s2);
        u16 s3 = bf16_rn(r2);
        Ut1[o] = s1; Ut2[o] = s2; Ut3[o] = s3;
    }
}

// ---------------------------------------------------------------------------
__global__ __launch_bounds__(256) void xw_gemm(const float* __restrict__ inp,
                                               const float* __restrict__ W,
                                               const float* __restrict__ bias,
                                               float* __restrict__ xW) {
    __shared__ float xs[8 * FEAT];
    int t = blockIdx.x;
    int b0 = blockIdx.y * 8;
    int tid = threadIdx.x;

    for (int i = tid; i < 8 * FEAT; i += 256) {
        int j = i / FEAT;
        int f = i - j * FEAT;
        xs[i] = inp[((size_t)(b0 + j) * T_STEPS + t) * FEAT + f];
    }
    __syncthreads();

    float bv[4];
    #pragma unroll
    for (int c = 0; c < 4; ++c) bv[c] = bias[tid + c * 256];

    float acc[8][4];
    #pragma unroll
    for (int j = 0; j < 8; ++j)
        #pragma unroll
        for (int c = 0; c < 4; ++c) acc[j][c] = bv[c];

    for (int f = 0; f < FEAT; ++f) {
        float w0 = W[(size_t)f * UNITS + tid];
        float w1 = W[(size_t)f * UNITS + tid + 256];
        float w2 = W[(size_t)f * UNITS + tid + 512];
        float w3 = W[(size_t)f * UNITS + tid + 768];
        #pragma unroll
        for (int j = 0; j < 8; ++j) {
            float xv = xs[j * FEAT + f];
            acc[j][0] += xv * w0;
            acc[j][1] += xv * w1;
            acc[j][2] += xv * w2;
            acc[j][3] += xv * w3;
        }
    }

    #pragma unroll
    for (int j = 0; j < 8; ++j)
        #pragma unroll
        for (int c = 0; c < 4; ++c)
            xW[((size_t)t * BATCH + b0 + j) * UNITS + tid + c * 256] = acc[j][c];
}

// ---------------------------------------------------------------------------
// One-hop tagged-dataflow MFMA scan. 128 blocks x 512 threads (8 waves).
// Block (g 0..3, slot 0..31): rows [g*16,+16) (row = dir*32+b), cols [slot*32,+32).
// Exchange: h as (tag<<32 | fp32bits) in one 8B agent store. Tags carry ALL
// correctness; the per-block flag is only a HINT (stored fire-and-forget, no
// vmcnt drain anywhere on the critical path). Reader wave kq: polls the 4
// source flags (one 16B load/iter — round-5's non-congesting pattern), then
// loads its tagged A words and verifies tags, retrying only on the rare
// in-flight store. Expected tag at step t is t (init tag 0 = h0); writer at
// step t stores tag t+1 into the other buffer.
// WAR-safe with 2 buffers: a block reaching its step-(t+1) store has
// tag-verified data of step t+1 from slots {4kq+0..3 | kq=0..7} = all 32
// group members, so every member completed its step-t loads.
// Epilogue distributed across all 8 waves: wave kq owns slice
// (nq=kq>>2, reg=kq&3); reduce = 8 conflict-free b128 LDS reads + vector add;
// each lane stores exactly one tagged word. LDS done-counter: last wave to
// finish publishes the flag hint.
__global__ __launch_bounds__(512) void rnn_scan(
        const float* __restrict__ xW,
        const u16* __restrict__ Ut1, const u16* __restrict__ Ut2,
        const u16* __restrict__ Ut3,
        u64* __restrict__ htag, u32* __restrict__ flags,
        float* __restrict__ out) {
    __shared__ f32x4 red[2][16][64];   // 32 KB, parity-alternating
    __shared__ u32 done[2];

    const int tid  = threadIdx.x;
    const int bk   = blockIdx.x;
    const int lane = tid & 63;
    const int kq   = tid >> 6;       // wave 0..7: k-slice [kq*128,+128)
    const int quad = lane >> 4;
    const int n16  = lane & 15;
    const int g    = bk & 3;
    const int slot = bk >> 2;
    const int R0   = g * 16;
    const int u0   = slot * 32;
    const int dir  = g >> 1;

    if (tid < 2) done[tid] = 0u;     // visible to all after first sync

    // epilogue role: wave kq owns (nq_e, reg_e); lane -> one C element
    const int nq_e  = kq >> 2;
    const int reg_e = kq & 3;
    const int erow  = R0 + ((lane >> 4) << 2) + reg_e;
    const int ecol  = u0 + nq_e * 16 + n16;
    const int eb    = erow & 31;                       // batch row for xW
    u64* edst = htag + (size_t)erow * UNITS + ecol;    // + db per step
    const float* exw = xW + (size_t)eb * UNITS + ecol; // + xt*B*U per step

    u32* myflag = flags + g * 32 + slot;
    const u64* fpoll = (const u64*)(flags + g * 32 + kq * 4);  // 16B aligned

    // --- B fragments: U splits, 96 VGPRs, loaded once (atomic -> pinned) ---
    short8 bfr[4][2][3];
    #pragma unroll
    for (int ks = 0; ks < 4; ++ks) {
        const int koff = kq * 128 + ks * 32 + quad * 8;
        #pragma unroll
        for (int nq = 0; nq < 2; ++nq) {
            const size_t ub = (size_t)(u0 + nq * 16 + n16) * UNITS + koff;
            bfr[ks][nq][0] = ld_agent_b16x8(Ut1 + ub);
            bfr[ks][nq][1] = ld_agent_b16x8(Ut2 + ub);
            bfr[ks][nq][2] = ld_agent_b16x8(Ut3 + ub);
        }
    }

    const size_t HS = (size_t)64 * UNITS;      // u64 elems per buffer

    for (int t = 0; t < T_STEPS; ++t) {
        const size_t sb = (size_t)(t & 1) * HS;
        const size_t db = sb ^ HS;
        const int par = t & 1;
        const u32 tagv = (u32)t;

        // xW for this thread's epilogue element (issued early)
        const int xt = dir ? (T_STEPS - 1 - t) : t;
        const float xwv = exw[(size_t)xt * (BATCH * UNITS)];

        // ---- flag hint: wait until the 4 source writers claim tag-t issued
        for (;;) {
            u64 qa = ld_agent_u64(fpoll);
            u64 qb = ld_agent_u64(fpoll + 1);
            if ((u32)qa >= tagv && (u32)(qa >> 32) >= tagv &&
                (u32)qb >= tagv && (u32)(qb >> 32) >= tagv) break;
        }

        // ---- tagged A loads (self-validating) + split + MFMA ----
        f32x4 acc[2][2] = {{{0.f,0.f,0.f,0.f},{0.f,0.f,0.f,0.f}},
                           {{0.f,0.f,0.f,0.f},{0.f,0.f,0.f,0.f}}};
        #pragma unroll
        for (int ks = 0; ks < 4; ++ks) {
            const u64* src = htag + sb + (size_t)(R0 + n16) * UNITS +
                             kq * 128 + ks * 32 + quad * 8;
            u64 p[8];
            for (;;) {
                #pragma unroll
                for (int j = 0; j < 8; ++j) p[j] = ld_agent_u64(src + j);
                int ok = 1;
                #pragma unroll
                for (int j = 0; j < 8; ++j) ok &= ((u32)(p[j] >> 32) == tagv);
                if (__all(ok)) break;
            }
            short8 a1, a2, a3;
            #pragma unroll
            for (int j = 0; j < 8; ++j) {
                u32 xb = (u32)p[j];
                float x = __uint_as_float(xb);
                u16 s1 = (u16)(xb >> 16);
                float r1 = x - bf16_f(s1);
                u16 s2 = (u16)(__float_as_uint(r1) >> 16);
                float r2 = r1 - bf16_f(s2);
                u16 s3 = (u16)(__float_as_uint(r2) >> 16);
                a1[j] = (short)s1; a2[j] = (short)s2; a3[j] = (short)s3;
            }
            #pragma unroll
            for (int nq = 0; nq < 2; ++nq) {
                acc[nq][0] = __builtin_amdgcn_mfma_f32_16x16x32_bf16(a1, bfr[ks][nq][0], acc[nq][0], 0, 0, 0);
                acc[nq][1] = __builtin_amdgcn_mfma_f32_16x16x32_bf16(a2, bfr[ks][nq][0], acc[nq][1], 0, 0, 0);
                acc[nq][0] = __builtin_amdgcn_mfma_f32_16x16x32_bf16(a1, bfr[ks][nq][1], acc[nq][0], 0, 0, 0);
                acc[nq][1] = __builtin_amdgcn_mfma_f32_16x16x32_bf16(a2, bfr[ks][nq][1], acc[nq][1], 0, 0, 0);
                acc[nq][0] = __builtin_amdgcn_mfma_f32_16x16x32_bf16(a1, bfr[ks][nq][2], acc[nq][0], 0, 0, 0);
                acc[nq][1] = __builtin_amdgcn_mfma_f32_16x16x32_bf16(a3, bfr[ks][nq][0], acc[nq][1], 0, 0, 0);
            }
        }

        // ---- dump partials (parity buffer); ONE sync per step ----
        red[par][kq * 2 + 0][lane] = acc[0][0] + acc[0][1];
        red[par][kq * 2 + 1][lane] = acc[1][0] + acc[1][1];
        __syncthreads();

        // ---- distributed reduce: 8 b128 reads (round-5 layout, 0 conflicts)
        f32x4 v = red[par][nq_e][lane];
        #pragma unroll
        for (int w = 1; w < 8; ++w) v += red[par][w * 2 + nq_e][lane];
        float a = fminf(fmaxf(selv(v, reg_e) + xwv, 0.f), CLIPV);
        st_agent_u64(edst + db,
                     ((u64)(u32)(t + 1) << 32) | (u64)__float_as_uint(a));

        // ---- flag hint from the last-finishing wave (fire-and-forget) ----
        if (lane == 0) {
            u32 old = __hip_atomic_fetch_add(&done[par], 1u, __ATOMIC_RELAXED,
                                             __HIP_MEMORY_SCOPE_WORKGROUP);
            if (old == 7u) {
                done[par] = 0u;
                st_agent_u32(myflag, (u32)(t + 1));
            }
        }
    }

    // ---- output: out = hf + hb; tag==800 self-validating, buffer 0 ----
    if (g < 2) {
        const int r = tid >> 5, c = tid & 31;
        const u64* pf = htag + (size_t)(R0 + r) * UNITS + u0 + c;
        const u64* pb = htag + (size_t)(R0 + r + 32) * UNITS + u0 + c;
        u64 vf, vb;
        while ((u32)((vf = ld_agent_u64(pf)) >> 32) != (u32)T_STEPS) {}
        while ((u32)((vb = ld_agent_u64(pb)) >> 32) != (u32)T_STEPS) {}
        out[(size_t)(R0 + r) * UNITS + u0 + c] =
            __uint_as_float((u32)vf) + __uint_as_float((u32)vb);
    }
}

// ---------------------------------------------------------------------------
extern "C" void kernel_launch(void* const* d_in, const int* in_sizes, int n_in,
                              void* d_out, int out_size, void* d_ws, size_t ws_size,
                              hipStream_t stream) {
    const float* inp  = (const float*)d_in[0];   // [32][800][161]
    const float* W    = (const float*)d_in[1];   // [161][1024]
    const float* U    = (const float*)d_in[2];   // [1024][1024]
    const float* bias = (const float*)d_in[3];   // [1024]
    float* out = (float*)d_out;                  // [32][1024]

    u16*   Ut1 = (u16*)d_ws;                              // 3 x 2 MB bf16 planes
    u16*   Ut2 = Ut1 + (size_t)UNITS * UNITS;
    u16*   Ut3 = Ut2 + (size_t)UNITS * UNITS;
    float* xW  = (float*)(Ut3 + (size_t)UNITS * UNITS);   // 104.9 MB
    u64*   htag = (u64*)(xW + (size_t)T_STEPS * BATCH * UNITS);  // 2 x 512 KB
    u32*   flags = (u32*)(htag + (size_t)2 * 64 * UNITS); // 128 words

    init_ws<<<64, 256, 0, stream>>>(htag, flags);
    u_split_t<<<dim3(32, 32), 256, 0, stream>>>(U, Ut1, Ut2, Ut3);
    xw_gemm<<<dim3(800, 4), 256, 0, stream>>>(inp, W, bias, xW);

    void* args[] = {(void*)&xW, (void*)&Ut1, (void*)&Ut2, (void*)&Ut3,
                    (void*)&htag, (void*)&flags, (void*)&out};
    hipLaunchCooperativeKernel((const void*)rnn_scan, dim3(128), dim3(512),
                               args, 0, stream);
}

// Round 10
// 8285.389 us; speedup vs baseline: 1.1398x; 1.1398x over previous
//
#include <hip/hip_runtime.h>
#include <hip/hip_bf16.h>

#define T_STEPS 800
#define BATCH   32
#define FEAT    161
#define UNITS   1024
#define CLIPV   20.0f

typedef __attribute__((ext_vector_type(8))) short short8;
typedef __attribute__((ext_vector_type(4))) float f32x4;
typedef unsigned short u16;
typedef unsigned int   u32;
typedef unsigned long long u64;

__device__ __forceinline__ float bf16_f(u16 u) {
    return __uint_as_float(((u32)u) << 16);
}
__device__ __forceinline__ u16 bf16_rn(float x) {
    __hip_bfloat16 b = __float2bfloat16(x);
    return *(u16*)&b;
}
__device__ __forceinline__ u64 ld_agent_u64(const u64* p) {
    return __hip_atomic_load(p, __ATOMIC_RELAXED, __HIP_MEMORY_SCOPE_AGENT);
}
__device__ __forceinline__ void st_agent_u64(u64* p, u64 v) {
    __hip_atomic_store(p, v, __ATOMIC_RELAXED, __HIP_MEMORY_SCOPE_AGENT);
}
__device__ __forceinline__ void st_agent_u32(u32* p, u32 v) {
    __hip_atomic_store(p, v, __ATOMIC_RELAXED, __HIP_MEMORY_SCOPE_AGENT);
}
__device__ __forceinline__ short8 ld_agent_b16x8(const u16* p) {
    union { u64 q[2]; short8 v; } u;
    u.q[0] = ld_agent_u64((const u64*)p);
    u.q[1] = ld_agent_u64((const u64*)p + 1);
    return u.v;
}
__device__ __forceinline__ float selv(f32x4 v, int r) {
    float s = v.x;
    s = (r == 1) ? v.y : s;
    s = (r == 2) ? v.z : s;
    s = (r == 3) ? v.w : s;
    return s;
}

// ---------------------------------------------------------------------------
// zero tagged h double-buffer (2 x 64 x 1024 u64; tag0|0.0f == 0) + flags
__global__ __launch_bounds__(256) void init_ws(u64* htag, u32* flags) {
    int gid = blockIdx.x * 256 + threadIdx.x;          // 16384 threads
    for (int i = gid; i < 2 * 64 * UNITS; i += 64 * 256) htag[i] = 0ull;
    if (gid < 128) flags[gid] = 0u;
}

// ---------------------------------------------------------------------------
// Ut splits: U[k][u] fp32 -> Ut1/2/3[u][k] bf16 (hi/mid/lo, 24-bit total)
__global__ __launch_bounds__(256) void u_split_t(const float* __restrict__ U,
                                                 u16* __restrict__ Ut1,
                                                 u16* __restrict__ Ut2,
                                                 u16* __restrict__ Ut3) {
    __shared__ float tile[32][33];
    int bx = blockIdx.x, by = blockIdx.y;
    int lx = threadIdx.x & 31;
    int ly4 = (threadIdx.x >> 5) * 4;
    #pragma unroll
    for (int j = 0; j < 4; ++j)
        tile[ly4 + j][lx] = U[(size_t)(by * 32 + ly4 + j) * UNITS + bx * 32 + lx];
    __syncthreads();
    #pragma unroll
    for (int j = 0; j < 4; ++j) {
        float x = tile[lx][ly4 + j];
        size_t o = (size_t)(bx * 32 + ly4 + j) * UNITS + by * 32 + lx;
        u16 s1 = bf16_rn(x);  float r1 = x - bf16_f(s1);
        u16 s2 = bf16_rn(r1); float r2 = r1 - bf16_f(s2);
        u16 s3 = bf16_rn(r2);
        Ut1[o] = s1; Ut2[o] = s2; Ut3[o] = s3;
    }
}

// ---------------------------------------------------------------------------
__global__ __launch_bounds__(256) void xw_gemm(const float* __restrict__ inp,
                                               const float* __restrict__ W,
                                               const float* __restrict__ bias,
                                               float* __restrict__ xW) {
    __shared__ float xs[8 * FEAT];
    int t = blockIdx.x;
    int b0 = blockIdx.y * 8;
    int tid = threadIdx.x;

    for (int i = tid; i < 8 * FEAT; i += 256) {
        int j = i / FEAT;
        int f = i - j * FEAT;
        xs[i] = inp[((size_t)(b0 + j) * T_STEPS + t) * FEAT + f];
    }
    __syncthreads();

    float bv[4];
    #pragma unroll
    for (int c = 0; c < 4; ++c) bv[c] = bias[tid + c * 256];

    float acc[8][4];
    #pragma unroll
    for (int j = 0; j < 8; ++j)
        #pragma unroll
        for (int c = 0; c < 4; ++c) acc[j][c] = bv[c];

    for (int f = 0; f < FEAT; ++f) {
        float w0 = W[(size_t)f * UNITS + tid];
        float w1 = W[(size_t)f * UNITS + tid + 256];
        float w2 = W[(size_t)f * UNITS + tid + 512];
        float w3 = W[(size_t)f * UNITS + tid + 768];
        #pragma unroll
        for (int j = 0; j < 8; ++j) {
            float xv = xs[j * FEAT + f];
            acc[j][0] += xv * w0;
            acc[j][1] += xv * w1;
            acc[j][2] += xv * w2;
            acc[j][3] += xv * w3;
        }
    }

    #pragma unroll
    for (int j = 0; j < 8; ++j)
        #pragma unroll
        for (int c = 0; c < 4; ++c)
            xW[((size_t)t * BATCH + b0 + j) * UNITS + tid + c * 256] = acc[j][c];
}

// ---------------------------------------------------------------------------
// Speculative tagged-dataflow MFMA scan. 128 blocks x 512 threads (8 waves).
// Block (g 0..3, slot 0..31): rows [g*16,+16) (row = dir*32+b), cols [slot*32,+32).
// Exchange: h word = (tag<<32 | fp32bits), one 8B agent store/load.
// Per step, wave kq (k-slice [kq*128,+128)):
//   1) SPECULATIVE load of all 4 k-subslices straightline (32 independent 8B
//      loads -> ~1 coherence RT, not 4). If all 32 tags == t: done, no poll.
//   2) else: poll the 4 source-block flags (one 16B load/iter; flags are
//      published AFTER each writer's vmcnt drain -> flag>=t implies data
//      visible) and reload once. Safety retry loop is dead code by that
//      guarantee. Max 2 load rounds/step -> retry storms impossible.
// Epilogue distributed (R9 layout, conflict-free): dump -> sync -> each of
// 512 threads reduces 8 b128 rows + stores ONE tagged word -> sync (drains
// every wave's stores) -> tid0 publishes flag = t+1. R5 flag semantics.
// WAR-safe with 2 buffers (transitive: a writer at step t+1 tag-verified all
// 32 members' t+1 tiles, so every member finished its step-t loads; blocks
// store only after the all-wave barrier, so no early overwrite).
__global__ __launch_bounds__(512) void rnn_scan(
        const float* __restrict__ xW,
        const u16* __restrict__ Ut1, const u16* __restrict__ Ut2,
        const u16* __restrict__ Ut3,
        u64* __restrict__ htag, u32* __restrict__ flags,
        float* __restrict__ out) {
    __shared__ f32x4 red[16][64];    // 16 KB

    const int tid  = threadIdx.x;
    const int bk   = blockIdx.x;
    const int lane = tid & 63;
    const int kq   = tid >> 6;       // wave 0..7
    const int quad = lane >> 4;
    const int n16  = lane & 15;
    const int g    = bk & 3;
    const int slot = bk >> 2;
    const int R0   = g * 16;
    const int u0   = slot * 32;
    const int dir  = g >> 1;

    // epilogue role: wave kq owns (nq_e = kq>>2, reg_e = kq&3)
    const int nq_e  = kq >> 2;
    const int reg_e = kq & 3;
    const int erow  = R0 + ((lane >> 4) << 2) + reg_e;
    const int ecol  = u0 + nq_e * 16 + n16;
    const int eb    = erow & 31;
    u64* edst = htag + (size_t)erow * UNITS + ecol;
    const float* exw = xW + (size_t)eb * UNITS + ecol;

    u32* myflag = flags + g * 32 + slot;
    const u64* fpoll = (const u64*)(flags + g * 32 + kq * 4);  // 16B aligned

    // --- B fragments: U splits for this wave's k-slice ---
    short8 bfr[4][2][3];
    #pragma unroll
    for (int ks = 0; ks < 4; ++ks) {
        const int koff = kq * 128 + ks * 32 + quad * 8;
        #pragma unroll
        for (int nq = 0; nq < 2; ++nq) {
            const size_t ub = (size_t)(u0 + nq * 16 + n16) * UNITS + koff;
            bfr[ks][nq][0] = ld_agent_b16x8(Ut1 + ub);
            bfr[ks][nq][1] = ld_agent_b16x8(Ut2 + ub);
            bfr[ks][nq][2] = ld_agent_b16x8(Ut3 + ub);
        }
    }

    const size_t HS = (size_t)64 * UNITS;      // u64 elems per buffer

    for (int t = 0; t < T_STEPS; ++t) {
        const size_t sb = (size_t)(t & 1) * HS;
        const size_t db = sb ^ HS;
        const u32 tagv = (u32)t;

        // xW for this thread's epilogue element (issued early, L3-resident)
        const int xt = dir ? (T_STEPS - 1 - t) : t;
        const float xwv = exw[(size_t)xt * (BATCH * UNITS)];

        // ---- 1) speculative tagged load: all 4 subslices straightline ----
        const u64* src = htag + sb + (size_t)(R0 + n16) * UNITS +
                         kq * 128 + quad * 8;
        u64 p[4][8];
        #pragma unroll
        for (int ks = 0; ks < 4; ++ks)
            #pragma unroll
            for (int j = 0; j < 8; ++j)
                p[ks][j] = ld_agent_u64(src + ks * 32 + j);
        int ok = 1;
        #pragma unroll
        for (int ks = 0; ks < 4; ++ks)
            #pragma unroll
            for (int j = 0; j < 8; ++j)
                ok &= ((u32)(p[ks][j] >> 32) == tagv);

        if (!__all(ok)) {
            // ---- 2) flag-gated reload (flags follow writers' vmcnt drain) --
            for (;;) {
                u64 qa = ld_agent_u64(fpoll);
                u64 qb = ld_agent_u64(fpoll + 1);
                if ((u32)qa >= tagv && (u32)(qa >> 32) >= tagv &&
                    (u32)qb >= tagv && (u32)(qb >> 32) >= tagv) break;
            }
            for (;;) {   // one pass in practice; loop is a correctness net
                #pragma unroll
                for (int ks = 0; ks < 4; ++ks)
                    #pragma unroll
                    for (int j = 0; j < 8; ++j)
                        p[ks][j] = ld_agent_u64(src + ks * 32 + j);
                int ok2 = 1;
                #pragma unroll
                for (int ks = 0; ks < 4; ++ks)
                    #pragma unroll
                    for (int j = 0; j < 8; ++j)
                        ok2 &= ((u32)(p[ks][j] >> 32) == tagv);
                if (__all(ok2)) break;
                __builtin_amdgcn_s_sleep(1);
            }
        }

        // ---- split to 3 bf16 planes + MFMA ----
        f32x4 acc[2][2] = {{{0.f,0.f,0.f,0.f},{0.f,0.f,0.f,0.f}},
                           {{0.f,0.f,0.f,0.f},{0.f,0.f,0.f,0.f}}};
        #pragma unroll
        for (int ks = 0; ks < 4; ++ks) {
            short8 a1, a2, a3;
            #pragma unroll
            for (int j = 0; j < 8; ++j) {
                u32 xb = (u32)p[ks][j];
                float x = __uint_as_float(xb);
                u16 s1 = (u16)(xb >> 16);
                float r1 = x - bf16_f(s1);
                u16 s2 = (u16)(__float_as_uint(r1) >> 16);
                float r2 = r1 - bf16_f(s2);
                u16 s3 = (u16)(__float_as_uint(r2) >> 16);
                a1[j] = (short)s1; a2[j] = (short)s2; a3[j] = (short)s3;
            }
            #pragma unroll
            for (int nq = 0; nq < 2; ++nq) {
                acc[nq][0] = __builtin_amdgcn_mfma_f32_16x16x32_bf16(a1, bfr[ks][nq][0], acc[nq][0], 0, 0, 0);
                acc[nq][1] = __builtin_amdgcn_mfma_f32_16x16x32_bf16(a2, bfr[ks][nq][0], acc[nq][1], 0, 0, 0);
                acc[nq][0] = __builtin_amdgcn_mfma_f32_16x16x32_bf16(a1, bfr[ks][nq][1], acc[nq][0], 0, 0, 0);
                acc[nq][1] = __builtin_amdgcn_mfma_f32_16x16x32_bf16(a2, bfr[ks][nq][1], acc[nq][1], 0, 0, 0);
                acc[nq][0] = __builtin_amdgcn_mfma_f32_16x16x32_bf16(a1, bfr[ks][nq][2], acc[nq][0], 0, 0, 0);
                acc[nq][1] = __builtin_amdgcn_mfma_f32_16x16x32_bf16(a3, bfr[ks][nq][0], acc[nq][1], 0, 0, 0);
            }
        }

        // ---- dump partials; distributed conflict-free reduce ----
        red[kq * 2 + 0][lane] = acc[0][0] + acc[0][1];
        red[kq * 2 + 1][lane] = acc[1][0] + acc[1][1];
        __syncthreads();

        f32x4 v = red[nq_e][lane];
        #pragma unroll
        for (int w = 1; w < 8; ++w) v += red[w * 2 + nq_e][lane];
        float a = fminf(fmaxf(selv(v, reg_e) + xwv, 0.f), CLIPV);
        st_agent_u64(edst + db,
                     ((u64)(u32)(t + 1) << 32) | (u64)__float_as_uint(a));

        // barrier drains EVERY wave's store (compiler: vmcnt(0) before
        // s_barrier) and protects red[] -> then publish the R5-style flag.
        __syncthreads();
        if (tid == 0) st_agent_u32(myflag, (u32)(t + 1));
    }

    // ---- output: out = hf + hb; tag==800 self-validating, buffer 0 ----
    if (g < 2) {
        const int r = tid >> 5, c = tid & 31;
        const u64* pf = htag + (size_t)(R0 + r) * UNITS + u0 + c;
        const u64* pb = htag + (size_t)(R0 + r + 32) * UNITS + u0 + c;
        u64 vf, vb;
        while ((u32)((vf = ld_agent_u64(pf)) >> 32) != (u32)T_STEPS)
            __builtin_amdgcn_s_sleep(1);
        while ((u32)((vb = ld_agent_u64(pb)) >> 32) != (u32)T_STEPS)
            __builtin_amdgcn_s_sleep(1);
        out[(size_t)(R0 + r) * UNITS + u0 + c] =
            __uint_as_float((u32)vf) + __uint_as_float((u32)vb);
    }
}

// ---------------------------------------------------------------------------
extern "C" void kernel_launch(void* const* d_in, const int* in_sizes, int n_in,
                              void* d_out, int out_size, void* d_ws, size_t ws_size,
                              hipStream_t stream) {
    const float* inp  = (const float*)d_in[0];   // [32][800][161]
    const float* W    = (const float*)d_in[1];   // [161][1024]
    const float* U    = (const float*)d_in[2];   // [1024][1024]
    const float* bias = (const float*)d_in[3];   // [1024]
    float* out = (float*)d_out;                  // [32][1024]

    u16*   Ut1 = (u16*)d_ws;                              // 3 x 2 MB bf16 planes
    u16*   Ut2 = Ut1 + (size_t)UNITS * UNITS;
    u16*   Ut3 = Ut2 + (size_t)UNITS * UNITS;
    float* xW  = (float*)(Ut3 + (size_t)UNITS * UNITS);   // 104.9 MB
    u64*   htag = (u64*)(xW + (size_t)T_STEPS * BATCH * UNITS);  // 2 x 512 KB
    u32*   flags = (u32*)(htag + (size_t)2 * 64 * UNITS); // 128 words

    init_ws<<<64, 256, 0, stream>>>(htag, flags);
    u_split_t<<<dim3(32, 32), 256, 0, stream>>>(U, Ut1, Ut2, Ut3);
    xw_gemm<<<dim3(800, 4), 256, 0, stream>>>(inp, W, bias, xW);

    void* args[] = {(void*)&xW, (void*)&Ut1, (void*)&Ut2, (void*)&Ut3,
                    (void*)&htag, (void*)&flags, (void*)&out};
    hipLaunchCooperativeKernel((const void*)rnn_scan, dim3(128), dim3(512),
                               args, 0, stream);
}